// Round 1
// baseline (3023.887 us; speedup 1.0000x reference)
//
#include <hip/hip_runtime.h>

#define NCH 64      // HID = OUT = 64
#define INF 128     // IN = 128

// ---------------- degrees ----------------
__global__ void k_deg(const int* __restrict__ src, const int* __restrict__ dst,
                      float* __restrict__ deg_out, float* __restrict__ deg_in, int nE) {
    int t = blockIdx.x * blockDim.x + threadIdx.x;
    int stride = gridDim.x * blockDim.x;
    for (int e = t; e < nE; e += stride) {
        atomicAdd(&deg_out[src[e]], 1.0f);
        atomicAdd(&deg_in[dst[e]], 1.0f);
    }
}

// deg -> rsqrt(max(deg,1)), applied to the contiguous [deg_out|deg_in] block (2*n)
__global__ void k_rsqrt(float* __restrict__ d, int n2) {
    int t = blockIdx.x * blockDim.x + threadIdx.x;
    if (t < n2) d[t] = rsqrtf(fmaxf(d[t], 1.0f));
}

// ---------------- GEMM1: h1 = (feat * out_norm) @ W1 ----------------
__global__ __launch_bounds__(256) void k_gemm1(const float* __restrict__ feat,
                                               const float* __restrict__ W1,
                                               const float* __restrict__ out_norm,
                                               float* __restrict__ h1, int nN) {
    __shared__ float sW[INF * NCH];  // 32 KB
    __shared__ float sF[4 * INF];    // 2 KB
    for (int i = threadIdx.x; i < INF * NCH; i += 256) sW[i] = W1[i];
    const int c = threadIdx.x & 63;
    const int rsub = threadIdx.x >> 6;
    for (int r0 = blockIdx.x * 4; r0 < nN; r0 += gridDim.x * 4) {
        __syncthreads();  // protects sW (first iter) and sF reuse
        {
            int i = threadIdx.x;
            int r1 = r0 + (i >> 7);
            sF[i] = (r1 < nN) ? feat[(long)r1 * INF + (i & 127)] : 0.0f;
            int i2 = i + 256;
            int r2 = r0 + (i2 >> 7);
            sF[i2] = (r2 < nN) ? feat[(long)r2 * INF + (i2 & 127)] : 0.0f;
        }
        __syncthreads();
        int row = r0 + rsub;
        if (row < nN) {
            float acc = 0.0f;
#pragma unroll
            for (int k = 0; k < INF; k += 4) {
                float4 f = *(const float4*)&sF[rsub * INF + k];
                acc += f.x * sW[(k + 0) * NCH + c];
                acc += f.y * sW[(k + 1) * NCH + c];
                acc += f.z * sW[(k + 2) * NCH + c];
                acc += f.w * sW[(k + 3) * NCH + c];
            }
            h1[(long)row * NCH + c] = acc * out_norm[row];
        }
    }
}

// ---------------- scatter: agg[dst] += h[src], 16 threads/edge, float4 ----------------
__global__ void k_scatter(const float* __restrict__ h, const int* __restrict__ src,
                          const int* __restrict__ dst, float* __restrict__ agg, int nE) {
    int t = blockIdx.x * blockDim.x + threadIdx.x;
    int e = t >> 4;
    if (e >= nE) return;
    int c4 = (t & 15) * 4;
    int s = src[e];
    int d = dst[e];
    const float4 v = *(const float4*)&h[(long)s * NCH + c4];
    float* out = &agg[(long)d * NCH + c4];
    atomicAdd(out + 0, v.x);
    atomicAdd(out + 1, v.y);
    atomicAdd(out + 2, v.z);
    atomicAdd(out + 3, v.w);
}

// ---------------- epilogue L1 fused with L2 pre-scale ----------------
// hb := out_norm * relu(hb * in_norm + b1)
__global__ void k_epi1(float* __restrict__ hb, const float* __restrict__ b1,
                       const float* __restrict__ norms /* [deg_out|deg_in] as rsqrt */,
                       int nN) {
    int t = blockIdx.x * blockDim.x + threadIdx.x;
    int node = t >> 4;
    if (node >= nN) return;
    int c4 = (t & 15) * 4;
    const float* out_norm = norms;
    const float* in_norm = norms + nN;
    float4 v = *(float4*)&hb[(long)node * NCH + c4];
    float4 b = *(const float4*)&b1[c4];
    float inn = in_norm[node];
    float onn = out_norm[node];
    v.x = fmaxf(v.x * inn + b.x, 0.0f) * onn;
    v.y = fmaxf(v.y * inn + b.y, 0.0f) * onn;
    v.z = fmaxf(v.z * inn + b.z, 0.0f) * onn;
    v.w = fmaxf(v.w * inn + b.w, 0.0f) * onn;
    *(float4*)&hb[(long)node * NCH + c4] = v;
}

// ---------------- GEMM2: out = (agg @ W2) * in_norm + b2 ----------------
__global__ __launch_bounds__(256) void k_gemm2(const float* __restrict__ agg,
                                               const float* __restrict__ W2,
                                               const float* __restrict__ in_norm,
                                               const float* __restrict__ b2,
                                               float* __restrict__ out, int nN) {
    __shared__ float sW[NCH * NCH];  // 16 KB
    __shared__ float sF[4 * NCH];    // 1 KB
    for (int i = threadIdx.x; i < NCH * NCH; i += 256) sW[i] = W2[i];
    const int c = threadIdx.x & 63;
    const int rsub = threadIdx.x >> 6;
    for (int r0 = blockIdx.x * 4; r0 < nN; r0 += gridDim.x * 4) {
        __syncthreads();
        {
            int i = threadIdx.x;
            int r1 = r0 + (i >> 6);
            sF[i] = (r1 < nN) ? agg[(long)r1 * NCH + (i & 63)] : 0.0f;
        }
        __syncthreads();
        int row = r0 + rsub;
        if (row < nN) {
            float acc = 0.0f;
#pragma unroll
            for (int k = 0; k < NCH; k += 4) {
                float4 f = *(const float4*)&sF[rsub * NCH + k];
                acc += f.x * sW[(k + 0) * NCH + c];
                acc += f.y * sW[(k + 1) * NCH + c];
                acc += f.z * sW[(k + 2) * NCH + c];
                acc += f.w * sW[(k + 3) * NCH + c];
            }
            out[(long)row * NCH + c] = acc * in_norm[row] + b2[c];
        }
    }
}

extern "C" void kernel_launch(void* const* d_in, const int* in_sizes, int n_in,
                              void* d_out, int out_size, void* d_ws, size_t ws_size,
                              hipStream_t stream) {
    const float* feat = (const float*)d_in[0];
    const int* src    = (const int*)d_in[1];
    const int* dst    = (const int*)d_in[2];
    const float* W1   = (const float*)d_in[3];
    const float* b1   = (const float*)d_in[4];
    const float* W2   = (const float*)d_in[5];
    const float* b2   = (const float*)d_in[6];
    float* out        = (float*)d_out;

    const int nN = in_sizes[0] / INF;   // 100000
    const int nE = in_sizes[1];         // 1600000

    // workspace layout (floats):
    //   [0, nN)          deg_out -> out_norm
    //   [nN, 2nN)        deg_in  -> in_norm
    //   [2nN, 2nN+64nN)  bufA: h1, later agg2
    //   [.., +64nN)      bufB: agg1 -> h2 (in place)
    float* ws = (float*)d_ws;
    float* norms = ws;              // 2*nN
    float* out_norm = ws;
    float* in_norm = ws + nN;
    float* bufA = ws + 2L * nN;     // nN*64
    float* bufB = bufA + (long)nN * NCH;

    // --- degrees & norms ---
    hipMemsetAsync(norms, 0, 2L * nN * sizeof(float), stream);
    k_deg<<<4096, 256, 0, stream>>>(src, dst, out_norm, in_norm, nE);
    k_rsqrt<<<(2 * nN + 255) / 256, 256, 0, stream>>>(norms, 2 * nN);

    // --- layer 1: h1 = (feat*out_norm)@W1 ---
    k_gemm1<<<1024, 256, 0, stream>>>(feat, W1, out_norm, bufA, nN);

    // --- scatter 1: agg1[dst] += h1[src] ---
    hipMemsetAsync(bufB, 0, (long)nN * NCH * sizeof(float), stream);
    {
        long threads = (long)nE * 16;
        int blocks = (int)((threads + 255) / 256);
        k_scatter<<<blocks, 256, 0, stream>>>(bufA, src, dst, bufB, nE);
    }

    // --- epilogue: h2 = out_norm * relu(agg1*in_norm + b1) (in place in bufB) ---
    k_epi1<<<(nN * 16 + 255) / 256, 256, 0, stream>>>(bufB, b1, norms, nN);

    // --- scatter 2: agg2[dst] += h2[src] (into bufA) ---
    hipMemsetAsync(bufA, 0, (long)nN * NCH * sizeof(float), stream);
    {
        long threads = (long)nE * 16;
        int blocks = (int)((threads + 255) / 256);
        k_scatter<<<blocks, 256, 0, stream>>>(bufB, src, dst, bufA, nE);
    }

    // --- layer 2 GEMM + epilogue: out = (agg2@W2)*in_norm + b2 ---
    k_gemm2<<<1024, 256, 0, stream>>>(bufA, W2, in_norm, b2, out, nN);
}

// Round 2
// 533.098 us; speedup vs baseline: 5.6723x; 5.6723x over previous
//
#include <hip/hip_runtime.h>

#define NCH 64      // HID = OUT = 64
#define INF 128     // IN = 128
#define SCAN_BS 256

// ---------------- int degrees ----------------
__global__ void k_deg_i(const int* __restrict__ src, const int* __restrict__ dst,
                        int* __restrict__ dout, int* __restrict__ din, int nE) {
    int t = blockIdx.x * blockDim.x + threadIdx.x;
    int stride = gridDim.x * blockDim.x;
    for (int e = t; e < nE; e += stride) {
        atomicAdd(&dout[src[e]], 1);
        atomicAdd(&din[dst[e]], 1);
    }
}

__global__ void k_norms(const int* __restrict__ dout, const int* __restrict__ din,
                        float* __restrict__ onorm, float* __restrict__ inorm, int nN) {
    int i = blockIdx.x * blockDim.x + threadIdx.x;
    if (i < nN) {
        onorm[i] = rsqrtf(fmaxf((float)dout[i], 1.0f));
        inorm[i] = rsqrtf(fmaxf((float)din[i], 1.0f));
    }
}

// ---------------- block scan for row_ptr (exclusive prefix over in-degree) ----------------
__global__ void k_scan_bsum(const int* __restrict__ cnt, int* __restrict__ bsum, int nN) {
    __shared__ int s[SCAN_BS];
    int i = blockIdx.x * SCAN_BS + threadIdx.x;
    s[threadIdx.x] = (i < nN) ? cnt[i] : 0;
    __syncthreads();
    for (int o = SCAN_BS / 2; o > 0; o >>= 1) {
        if (threadIdx.x < o) s[threadIdx.x] += s[threadIdx.x + o];
        __syncthreads();
    }
    if (threadIdx.x == 0) bsum[blockIdx.x] = s[0];
}

// single block, exclusive scan of up to 512 block sums; also writes row_ptr[nN] = nE
__global__ void k_scan_top(int* __restrict__ bsum, int nb, int* __restrict__ rp_last, int nE) {
    __shared__ int s[512];
    int t = threadIdx.x;
    int v = (t < nb) ? bsum[t] : 0;
    s[t] = v;
    __syncthreads();
    for (int o = 1; o < 512; o <<= 1) {
        int add = (t >= o) ? s[t - o] : 0;
        __syncthreads();
        s[t] += add;
        __syncthreads();
    }
    if (t < nb) bsum[t] = s[t] - v;  // exclusive
    if (t == 0) *rp_last = nE;
}

__global__ void k_scan_final(const int* __restrict__ cnt, const int* __restrict__ bsum,
                             int* __restrict__ row_ptr, int nN) {
    __shared__ int s[SCAN_BS];
    int i = blockIdx.x * SCAN_BS + threadIdx.x;
    int v = (i < nN) ? cnt[i] : 0;
    s[threadIdx.x] = v;
    __syncthreads();
    for (int o = 1; o < SCAN_BS; o <<= 1) {
        int add = (threadIdx.x >= o) ? s[threadIdx.x - o] : 0;
        __syncthreads();
        s[threadIdx.x] += add;
        __syncthreads();
    }
    if (i < nN) row_ptr[i] = bsum[blockIdx.x] + s[threadIdx.x] - v;  // exclusive
}

// ---------------- CSR bucket fill: col[] gets src ids grouped by dst ----------------
__global__ void k_fill(const int* __restrict__ src, const int* __restrict__ dst,
                       int* __restrict__ cursor, int* __restrict__ col, int nE) {
    int t = blockIdx.x * blockDim.x + threadIdx.x;
    int stride = gridDim.x * blockDim.x;
    for (int e = t; e < nE; e += stride) {
        int d = dst[e];
        int pos = atomicAdd(&cursor[d], 1);
        col[pos] = src[e];
    }
}

// ---------------- GEMM1: h1 = (feat * out_norm) @ W1 ----------------
__global__ __launch_bounds__(256) void k_gemm1(const float* __restrict__ feat,
                                               const float* __restrict__ W1,
                                               const float* __restrict__ out_norm,
                                               float* __restrict__ h1, int nN) {
    __shared__ float sW[INF * NCH];  // 32 KB
    __shared__ float sF[4 * INF];    // 2 KB
    for (int i = threadIdx.x; i < INF * NCH; i += 256) sW[i] = W1[i];
    const int c = threadIdx.x & 63;
    const int rsub = threadIdx.x >> 6;
    for (int r0 = blockIdx.x * 4; r0 < nN; r0 += gridDim.x * 4) {
        __syncthreads();
        {
            int i = threadIdx.x;
            int r1 = r0 + (i >> 7);
            sF[i] = (r1 < nN) ? feat[(long)r1 * INF + (i & 127)] : 0.0f;
            int i2 = i + 256;
            int r2 = r0 + (i2 >> 7);
            sF[i2] = (r2 < nN) ? feat[(long)r2 * INF + (i2 & 127)] : 0.0f;
        }
        __syncthreads();
        int row = r0 + rsub;
        if (row < nN) {
            float acc = 0.0f;
#pragma unroll
            for (int k = 0; k < INF; k += 4) {
                float4 f = *(const float4*)&sF[rsub * INF + k];
                acc += f.x * sW[(k + 0) * NCH + c];
                acc += f.y * sW[(k + 1) * NCH + c];
                acc += f.z * sW[(k + 2) * NCH + c];
                acc += f.w * sW[(k + 3) * NCH + c];
            }
            h1[(long)row * NCH + c] = acc * out_norm[row];
        }
    }
}

// ---------------- CSR gather-aggregate: one wave per dst node, lane = channel ----------------
// EPI==1: out = out_norm * relu(acc * in_norm + bias)   (layer-1 epilogue + layer-2 pre-scale)
// EPI==0: out = acc
template <int EPI>
__global__ __launch_bounds__(256) void k_agg(const float* __restrict__ h,
                                             const int* __restrict__ row_ptr,
                                             const int* __restrict__ col,
                                             float* __restrict__ out,
                                             const float* __restrict__ in_norm,
                                             const float* __restrict__ out_norm,
                                             const float* __restrict__ bias, int nN) {
    const int lane = threadIdx.x & 63;
    const int wpb = blockDim.x >> 6;
    int wid = blockIdx.x * wpb + (threadIdx.x >> 6);
    const int nw = gridDim.x * wpb;
    const float b = (EPI == 1) ? bias[lane] : 0.0f;
    for (int node = wid; node < nN; node += nw) {
        int beg = row_ptr[node];
        int end = row_ptr[node + 1];
        float acc = 0.0f;
        int e = beg;
        for (; e + 4 <= end; e += 4) {
            int s0 = col[e + 0], s1 = col[e + 1], s2 = col[e + 2], s3 = col[e + 3];
            float v0 = h[(long)s0 * NCH + lane];
            float v1 = h[(long)s1 * NCH + lane];
            float v2 = h[(long)s2 * NCH + lane];
            float v3 = h[(long)s3 * NCH + lane];
            acc += v0; acc += v1; acc += v2; acc += v3;
        }
        for (; e < end; ++e) acc += h[(long)col[e] * NCH + lane];
        if (EPI == 1) {
            out[(long)node * NCH + lane] = fmaxf(acc * in_norm[node] + b, 0.0f) * out_norm[node];
        } else {
            out[(long)node * NCH + lane] = acc;
        }
    }
}

// ---------------- GEMM2: out = (agg @ W2) * in_norm + b2 ----------------
__global__ __launch_bounds__(256) void k_gemm2(const float* __restrict__ agg,
                                               const float* __restrict__ W2,
                                               const float* __restrict__ in_norm,
                                               const float* __restrict__ b2,
                                               float* __restrict__ out, int nN) {
    __shared__ float sW[NCH * NCH];  // 16 KB
    __shared__ float sF[4 * NCH];    // 1 KB
    for (int i = threadIdx.x; i < NCH * NCH; i += 256) sW[i] = W2[i];
    const int c = threadIdx.x & 63;
    const int rsub = threadIdx.x >> 6;
    for (int r0 = blockIdx.x * 4; r0 < nN; r0 += gridDim.x * 4) {
        __syncthreads();
        {
            int i = threadIdx.x;
            int r1 = r0 + (i >> 6);
            sF[i] = (r1 < nN) ? agg[(long)r1 * NCH + (i & 63)] : 0.0f;
        }
        __syncthreads();
        int row = r0 + rsub;
        if (row < nN) {
            float acc = 0.0f;
#pragma unroll
            for (int k = 0; k < NCH; k += 4) {
                float4 f = *(const float4*)&sF[rsub * NCH + k];
                acc += f.x * sW[(k + 0) * NCH + c];
                acc += f.y * sW[(k + 1) * NCH + c];
                acc += f.z * sW[(k + 2) * NCH + c];
                acc += f.w * sW[(k + 3) * NCH + c];
            }
            out[(long)row * NCH + c] = acc * in_norm[row] + b2[c];
        }
    }
}

extern "C" void kernel_launch(void* const* d_in, const int* in_sizes, int n_in,
                              void* d_out, int out_size, void* d_ws, size_t ws_size,
                              hipStream_t stream) {
    const float* feat = (const float*)d_in[0];
    const int* src    = (const int*)d_in[1];
    const int* dst    = (const int*)d_in[2];
    const float* W1   = (const float*)d_in[3];
    const float* b1   = (const float*)d_in[4];
    const float* W2   = (const float*)d_in[5];
    const float* b2   = (const float*)d_in[6];
    float* out        = (float*)d_out;

    const int nN = in_sizes[0] / INF;   // 100000
    const int nE = in_sizes[1];         // 1600000

    // ---- workspace layout ----
    char* p = (char*)d_ws;
    float* out_norm = (float*)p;                 p += (size_t)nN * 4;
    float* in_norm  = (float*)p;                 p += (size_t)nN * 4;
    float* bufA     = (float*)p;                 p += (size_t)nN * NCH * 4;  // h1 / agg2
    float* bufB     = (float*)p;                 p += (size_t)nN * NCH * 4;  // h2
    int* deg_i      = (int*)p;                   p += (size_t)2 * nN * 4;    // [outdeg|indeg]
    int* outdeg_i   = deg_i;
    int* indeg_i    = deg_i + nN;
    int* row_ptr    = (int*)p;                   p += (size_t)(nN + 1) * 4;
    int* cursor     = (int*)p;                   p += (size_t)nN * 4;
    int* col        = (int*)p;                   p += (size_t)nE * 4;
    int* bsum       = (int*)p;                   p += 512 * 4;

    const int nb = (nN + SCAN_BS - 1) / SCAN_BS;  // 391 <= 512

    // ---- degrees & norms ----
    hipMemsetAsync(deg_i, 0, (size_t)2 * nN * 4, stream);
    k_deg_i<<<2048, 256, 0, stream>>>(src, dst, outdeg_i, indeg_i, nE);
    k_norms<<<(nN + 255) / 256, 256, 0, stream>>>(outdeg_i, indeg_i, out_norm, in_norm, nN);

    // ---- CSR build (by dst) ----
    k_scan_bsum<<<nb, SCAN_BS, 0, stream>>>(indeg_i, bsum, nN);
    k_scan_top<<<1, 512, 0, stream>>>(bsum, nb, row_ptr + nN, nE);
    k_scan_final<<<nb, SCAN_BS, 0, stream>>>(indeg_i, bsum, row_ptr, nN);
    hipMemcpyAsync(cursor, row_ptr, (size_t)nN * 4, hipMemcpyDeviceToDevice, stream);
    k_fill<<<2048, 256, 0, stream>>>(src, dst, cursor, col, nE);

    // ---- layer 1: h1 = (feat*out_norm)@W1 ----
    k_gemm1<<<1024, 256, 0, stream>>>(feat, W1, out_norm, bufA, nN);

    // ---- agg1 + epilogue(relu etc) fused: bufB = out_norm*relu(gather(bufA)*in_norm + b1) ----
    k_agg<1><<<(nN + 3) / 4, 256, 0, stream>>>(bufA, row_ptr, col, bufB,
                                               in_norm, out_norm, b1, nN);

    // ---- agg2: bufA = gather(bufB) ----
    k_agg<0><<<(nN + 3) / 4, 256, 0, stream>>>(bufB, row_ptr, col, bufA,
                                               in_norm, out_norm, b1, nN);

    // ---- layer 2 GEMM + epilogue: out = (bufA@W2)*in_norm + b2 ----
    k_gemm2<<<1024, 256, 0, stream>>>(bufA, W2, in_norm, b2, out, nN);
}